// Round 14
// baseline (239.701 us; speedup 1.0000x reference)
//
#include <hip/hip_runtime.h>
#include <hip/hip_bf16.h>
#include <math.h>

#define H 511
#define L 2048
#define NST 32
#define NLAYERS 4
#define LN_EPS 1e-5f
#define NCH 32             // chunks per channel (conv)
#define TC (L / NCH)       // 64 steps per chunk
#define HN (H * NST)       // 16352
#define HP 512             // K padded
#define GBK 64
#define GBN 64
#define NSTRIPE 16         // LN h-stripes of 32

typedef __attribute__((ext_vector_type(8))) short short8;
typedef __attribute__((ext_vector_type(4))) float f32x4;

__device__ __forceinline__ ushort f2bf(float v) {
    __hip_bfloat16 b = __float2bfloat16(v);
    return *reinterpret_cast<ushort*>(&b);
}

// ---------------------------------------------------------------------------
// Merged precompute: per-(h,n) coefs + w^64 (idx < HN) + W->bf16 (idx < 2H*HP).
// ---------------------------------------------------------------------------
__global__ __launch_bounds__(256) void pre_kernel(
    const float* __restrict__ log_dt,
    const float* __restrict__ A_real_log,
    const float* __restrict__ A_imag,
    const float* __restrict__ C_re,
    const float* __restrict__ C_im,
    const float* __restrict__ W,
    float* __restrict__ wr_o, float* __restrict__ wi_o,
    float* __restrict__ cr_o, float* __restrict__ ci_o,
    float* __restrict__ w64r_o, float* __restrict__ w64i_o,
    ushort* __restrict__ wbf)
{
    int idx = blockIdx.x * blockDim.x + threadIdx.x;
    if (idx < HN) {
        int h = idx / NST;
        float Ar = -expf(A_real_log[idx]);
        float Ai = A_imag[idx];
        float dt = expf(log_dt[h]);
        float dr = Ar * dt, di = Ai * dt;
        float er = expf(dr);
        float wr = er * cosf(di);
        float wi = er * sinf(di);
        float den = Ar * Ar + Ai * Ai;
        float a = wr - 1.0f, b = wi;
        float inv = 1.0f / den;
        float qr = (a * Ar + b * Ai) * inv;
        float qi = (b * Ar - a * Ai) * inv;
        wr_o[idx] = wr; wi_o[idx] = wi;
        cr_o[idx] = 2.0f * (C_re[idx] * qr - C_im[idx] * qi);
        ci_o[idx] = 2.0f * (C_re[idx] * qi + C_im[idx] * qr);
        // w^64 by 6 squarings
        float sr = wr, si = wi;
        #pragma unroll
        for (int k = 0; k < 6; ++k) {
            float nr = sr * sr - si * si;
            float ni = 2.0f * sr * si;
            sr = nr; si = ni;
        }
        w64r_o[idx] = sr; w64i_o[idx] = si;
    }
    if (idx < 2 * H * HP) {
        int r = idx / HP, k = idx % HP;
        float v = (k < H) ? W[(size_t)r * H + k] : 0.0f;
        wbf[idx] = f2bf(v);
    }
}

// ---------------------------------------------------------------------------
// DPP helpers: sum across each 32-lane half; result lands in lanes 31 and 63.
// ---------------------------------------------------------------------------
template <int CTRL, int ROW_MASK>
__device__ __forceinline__ float dpp_add(float x) {
    int r = __builtin_amdgcn_update_dpp(0, __float_as_int(x), CTRL, ROW_MASK, 0xf, true);
    return x + __int_as_float(r);
}
__device__ __forceinline__ float reduce32_to_lane31(float p) {
    p = dpp_add<0x111, 0xf>(p);  // row_shr:1
    p = dpp_add<0x112, 0xf>(p);  // row_shr:2
    p = dpp_add<0x114, 0xf>(p);  // row_shr:4
    p = dpp_add<0x118, 0xf>(p);  // row_shr:8
    p = dpp_add<0x142, 0xa>(p);  // row_bcast:15 into rows 1,3
    return p;                    // lane31 = sum(0..31), lane63 = sum(32..63)
}

__device__ __forceinline__ float gelu_tanh(float v) {
    const float c0 = 0.7978845608028654f;  // sqrt(2/pi)
    float t = tanhf(c0 * (v + 0.044715f * v * v * v));
    return 0.5f * v * (1.0f + t);
}

// ---------------------------------------------------------------------------
// Fused conv with inline LN of the input (absorbs prev layer's ln_apply):
// staged z = donorm ? (zsrc - mu[l])*rstd[l]*g[h]+b[h] : zsrc, and that value
// is ALSO written back to znorm (zbuf) so glu reads it as the residual.
// Phase2: Kogge-Stone chunk scan, bank-conflict-free via [NCH][33] padding.
// ---------------------------------------------------------------------------
__global__ __launch_bounds__(1024, 8) void conv_fused(
    const float* __restrict__ zsrc,    // (H,L): layer0 Z, else zpre (=out)
    const float* __restrict__ psum_p,  // prev-layer stats partials
    const float* __restrict__ psq_p,
    const float* __restrict__ lng,
    const float* __restrict__ lnb,
    const int donorm,
    const float* __restrict__ wr_,
    const float* __restrict__ wi_,
    const float* __restrict__ cr_,
    const float* __restrict__ ci_,
    const float* __restrict__ w64r_,
    const float* __restrict__ w64i_,
    const float* __restrict__ D_skip,
    float* __restrict__ znorm,         // (H,L) normalized z out (= zbuf)
    ushort* __restrict__ yb)           // (H,L) bf16
{
    __shared__ float zs[L];            // 8 KB
    __shared__ float ber[NCH][NST + 1];  // padded: conflict-free KS scan
    __shared__ float bei[NCH][NST + 1];
    __shared__ float ysf[L];           // 8 KB

    const int tid  = threadIdx.x;
    const int wv   = tid >> 6;          // wave 0..15
    const int half = (tid >> 5) & 1;
    const int ln   = tid & 31;          // state index n
    const int c    = wv * 2 + half;     // chunk 0..31
    const int h    = blockIdx.x;

    // stage z row (2 cols/thread) with optional inline LN + global writeback
    {
        const int c0 = tid * 2;
        float2 v = *(const float2*)&zsrc[(size_t)h * L + c0];
        if (donorm) {
            float2 S = {0.f, 0.f}, Q = {0.f, 0.f};
            #pragma unroll
            for (int k = 0; k < NSTRIPE; ++k) {
                float2 sv = *(const float2*)&psum_p[(size_t)k * L + c0];
                float2 qv = *(const float2*)&psq_p[(size_t)k * L + c0];
                S.x += sv.x; S.y += sv.y;
                Q.x += qv.x; Q.y += qv.y;
            }
            const float invH = 1.0f / (float)H;
            float mu0 = S.x * invH, mu1 = S.y * invH;
            float rs0 = rsqrtf(Q.x * invH - mu0 * mu0 + LN_EPS);
            float rs1 = rsqrtf(Q.y * invH - mu1 * mu1 + LN_EPS);
            float gh = lng[h], bh = lnb[h];
            v.x = (v.x - mu0) * rs0 * gh + bh;
            v.y = (v.y - mu1) * rs1 * gh + bh;
        }
        *(float2*)&zs[c0] = v;
        *(float2*)&znorm[(size_t)h * L + c0] = v;   // residual source for glu
    }

    const int cidx = h * NST + ln;
    const float wr = wr_[cidx], wi = wi_[cidx];
    const float cr = cr_[cidx], ci = ci_[cidx];
    const float Dh = D_skip[h];
    __syncthreads();

    // phase 1: local scan of chunk c (carry 0)
    float sr = 0.f, si = 0.f;
    {
        const float* zp = &zs[c * TC];
        #pragma unroll 8
        for (int l = 0; l < TC; ++l) {
            float zl = zp[l];
            float nsr = fmaf(wr, sr, fmaf(-wi, si, zl));
            float nsi = fmaf(wr, si, wi * sr);
            sr = nsr; si = nsi;
        }
    }
    ber[c][ln] = sr;
    bei[c][ln] = si;
    __syncthreads();

    // phase 2: Kogge-Stone scan across the 32 chunks, all threads active.
    {
        const int lam = tid & 63;
        const int c2 = lam & 31;
        const int n2 = ((tid >> 6) << 1) | (lam >> 5);
        float Ir = ber[c2][n2], Ii = bei[c2][n2];
        float Wr = w64r_[h * NST + n2], Wi = w64i_[h * NST + n2];
        #pragma unroll
        for (int d = 1; d < 32; d <<= 1) {
            float pr = __shfl_up(Ir, d, 32);
            float pi = __shfl_up(Ii, d, 32);
            if (c2 < d) { pr = 0.f; pi = 0.f; }
            float tr = fmaf(Wr, pr, -Wi * pi);
            float ti = fmaf(Wr, pi,  Wi * pr);
            Ir += tr; Ii += ti;
            float nWr = Wr * Wr - Wi * Wi;
            float nWi = 2.0f * Wr * Wi;
            Wr = nWr; Wi = nWi;
        }
        float Cr = __shfl_up(Ir, 1, 32);
        float Ci = __shfl_up(Ii, 1, 32);
        if (c2 == 0) { Cr = 0.f; Ci = 0.f; }
        __syncthreads();   // all reads of ber/bei done before overwrite
        ber[c2][n2] = Cr;
        bei[c2][n2] = Ci;
    }
    __syncthreads();

    // phase 3: rescan with carry + C-dot + reduce + D-skip (preactivation)
    sr = ber[c][ln];
    si = bei[c][ln];
    {
        const float* zp = &zs[c * TC];
        float* yp = &ysf[c * TC];
        #pragma unroll 4
        for (int l = 0; l < TC; ++l) {
            float zl = zp[l];
            float nsr = fmaf(wr, sr, fmaf(-wi, si, zl));
            float nsi = fmaf(wr, si, wi * sr);
            sr = nsr; si = nsi;
            float p = fmaf(cr, sr, -ci * si);
            p = reduce32_to_lane31(p);
            if (ln == 31) yp[l] = fmaf(Dh, zl, p);
        }
    }
    __syncthreads();

    // epilogue: all lanes, gelu + bf16, coalesced ushort2 stores
    {
        ushort2 v;
        v.x = f2bf(gelu_tanh(ysf[tid * 2]));
        v.y = f2bf(gelu_tanh(ysf[tid * 2 + 1]));
        *(ushort2*)&yb[(size_t)h * L + tid * 2] = v;
    }
}

// ---------------------------------------------------------------------------
// MFMA GLU GEMM + fused LN-stats (round-10 proven, unchanged).
// ---------------------------------------------------------------------------
__global__ __launch_bounds__(256) void glu_mfma(
    const ushort* __restrict__ wbf,   // (2H, HP) bf16
    const ushort* __restrict__ yb,    // (H, L) bf16
    const float* __restrict__ bias,   // (2H)
    const float* __restrict__ zres,   // (H,L) normalized residual (zbuf)
    float* __restrict__ out,          // (H,L)
    float* __restrict__ psum,         // (NSTRIPE,L)
    float* __restrict__ psq)          // (NSTRIPE,L)
{
    __shared__ ushort As1[32 * GBK];       // 4 KB
    __shared__ ushort As2[32 * GBK];       // 4 KB
    __shared__ ushort Bs[GBN * GBK];       // 8 KB
    __shared__ ushort tempT[4][32 * 40];   // 10 KB
    __shared__ float  sls[2][64];
    __shared__ float  slq[2][64];

    const int tid = threadIdx.x;
    const int h0 = blockIdx.y * 32;
    const int l0 = blockIdx.x * GBN;
    const int wid = tid >> 6;
    const int lane = tid & 63;
    const int wrow = (wid >> 1) * 16;
    const int wcol = (wid & 1) * 32;

    f32x4 acc1[2] = {{0.f,0.f,0.f,0.f},{0.f,0.f,0.f,0.f}};
    f32x4 acc2[2] = {{0.f,0.f,0.f,0.f},{0.f,0.f,0.f,0.f}};

    const int ar = tid >> 3;
    const int ak = tid & 7;
    const int hq1 = (h0 + ar < H) ? (h0 + ar) : (H - 1);
    const int hq2 = hq1 + H;
    const int aswz = ak ^ (ar & 7);

    const int tm   = tid >> 6;
    const int t64  = tid & 63;
    const int ksub = (tm & 1) * 32;
    const int lsub = (tm >> 1) * 32;
    const int bkl  = t64 >> 1;
    const int bhalf= t64 & 1;
    const int blr  = t64 >> 1;
    const int bkh  = t64 & 1;

    for (int k0 = 0; k0 < HP; k0 += GBK) {
        {
            short8 va1 = *(const short8*)&wbf[(size_t)hq1 * HP + k0 + ak * 8];
            short8 va2 = *(const short8*)&wbf[(size_t)hq2 * HP + k0 + ak * 8];
            *(short8*)&As1[ar * GBK + aswz * 8] = va1;
            *(short8*)&As2[ar * GBK + aswz * 8] = va2;
        }
        {
            const int kg = k0 + ksub + bkl;
            short8 v0 = {0,0,0,0,0,0,0,0}, v1 = {0,0,0,0,0,0,0,0};
            if (kg < H) {
                const ushort* row = &yb[(size_t)kg * L + l0 + lsub + bhalf * 16];
                v0 = *(const short8*)&row[0];
                v1 = *(const short8*)&row[8];
            }
            ushort* tp = &tempT[tm][0];
            #pragma unroll
            for (int j = 0; j < 8; ++j)
                tp[(bhalf * 16 + j) * 40 + bkl] = (ushort)v0[j];
            #pragma unroll
            for (int j = 0; j < 8; ++j)
                tp[(bhalf * 16 + 8 + j) * 40 + bkl] = (ushort)v1[j];
        }
        __syncthreads();
        {
            const ushort* tp = &tempT[tm][0];
            short8 b0 = *(const short8*)&tp[blr * 40 + bkh * 16];
            short8 b1 = *(const short8*)&tp[blr * 40 + bkh * 16 + 8];
            const int L_ = lsub + blr;
            const int kg0 = (ksub >> 3) + bkh * 2;
            *(short8*)&Bs[L_ * GBK + ((kg0    ) ^ (L_ & 7)) * 8] = b0;
            *(short8*)&Bs[L_ * GBK + ((kg0 + 1) ^ (L_ & 7)) * 8] = b1;
        }
        __syncthreads();

        #pragma unroll
        for (int kk = 0; kk < 2; ++kk) {
            const int arow = wrow + (lane & 15);
            const int kg = kk * 4 + (lane >> 4);
            short8 a1 = *(const short8*)&As1[arow * GBK + (kg ^ (arow & 7)) * 8];
            short8 a2 = *(const short8*)&As2[arow * GBK + (kg ^ (arow & 7)) * 8];
            #pragma unroll
            for (int nf = 0; nf < 2; ++nf) {
                const int brow = wcol + nf * 16 + (lane & 15);
                short8 b = *(const short8*)&Bs[brow * GBK + (kg ^ (brow & 7)) * 8];
                acc1[nf] = __builtin_amdgcn_mfma_f32_16x16x32_bf16(a1, b, acc1[nf], 0, 0, 0);
                acc2[nf] = __builtin_amdgcn_mfma_f32_16x16x32_bf16(a2, b, acc2[nf], 0, 0, 0);
            }
        }
        __syncthreads();
    }

    // ---- epilogue: GLU + residual -> out, plus LN partial stats ----
    float ps[2] = {0.f, 0.f}, pq[2] = {0.f, 0.f};
    #pragma unroll
    for (int nf = 0; nf < 2; ++nf) {
        const int col = l0 + wcol + nf * 16 + (lane & 15);
        #pragma unroll
        for (int r = 0; r < 4; ++r) {
            const int h = h0 + wrow + (lane >> 4) * 4 + r;
            if (h < H) {
                float v1 = acc1[nf][r] + bias[h];
                float v2 = acc2[nf][r] + bias[h + H];
                float o = v1 * (1.0f / (1.0f + expf(-v2))) + zres[(size_t)h * L + col];
                out[(size_t)h * L + col] = o;
                ps[nf] += o;
                pq[nf] = fmaf(o, o, pq[nf]);
            }
        }
    }
    #pragma unroll
    for (int nf = 0; nf < 2; ++nf) {
        ps[nf] += __shfl_xor(ps[nf], 16, 64);
        ps[nf] += __shfl_xor(ps[nf], 32, 64);
        pq[nf] += __shfl_xor(pq[nf], 16, 64);
        pq[nf] += __shfl_xor(pq[nf], 32, 64);
        if ((lane >> 4) == 0) {
            int cl = wcol + nf * 16 + lane;
            sls[wid >> 1][cl] = ps[nf];
            slq[wid >> 1][cl] = pq[nf];
        }
    }
    __syncthreads();
    if (tid < 64) {
        psum[(size_t)blockIdx.y * L + l0 + tid] = sls[0][tid] + sls[1][tid];
        psq [(size_t)blockIdx.y * L + l0 + tid] = slq[0][tid] + slq[1][tid];
    }
}

// ---------------------------------------------------------------------------
// Final LN apply (last layer only): in-place normalize out.
// ---------------------------------------------------------------------------
__global__ __launch_bounds__(256) void ln_apply(
    const float* __restrict__ psum, const float* __restrict__ psq,
    const float* __restrict__ g, const float* __restrict__ b,
    float* __restrict__ out)
{
    const int tx = threadIdx.x & 63;
    const int ty = threadIdx.x >> 6;
    const int l = blockIdx.x * 64 + tx;
    const int s = blockIdx.y;

    float S = 0.f, Q = 0.f;
    #pragma unroll
    for (int k = 0; k < NSTRIPE; ++k) {
        S += psum[(size_t)k * L + l];
        Q += psq[(size_t)k * L + l];
    }
    const float invH = 1.0f / (float)H;
    float mu = S * invH;
    float var = Q * invH - mu * mu;
    float rstd = rsqrtf(var + LN_EPS);

    const int hbase = s * 32;
    #pragma unroll
    for (int j = 0; j < 8; ++j) {
        int h = hbase + ty + j * 4;
        if (h < H) {
            float v = out[(size_t)h * L + l];
            out[(size_t)h * L + l] = (v - mu) * rstd * g[h] + b[h];
        }
    }
}

// ---------------------------------------------------------------------------
extern "C" void kernel_launch(void* const* d_in, const int* in_sizes, int n_in,
                              void* d_out, int out_size, void* d_ws, size_t ws_size,
                              hipStream_t stream) {
    const float* Z          = (const float*)d_in[0];
    const float* log_dt     = (const float*)d_in[1];
    const float* A_real_log = (const float*)d_in[2];
    const float* A_imag     = (const float*)d_in[3];
    const float* C_re       = (const float*)d_in[4];
    const float* C_im       = (const float*)d_in[5];
    const float* D_skip     = (const float*)d_in[6];
    const float* glu_w      = (const float*)d_in[7];
    const float* glu_b      = (const float*)d_in[8];
    const float* ln_g       = (const float*)d_in[9];
    const float* ln_b       = (const float*)d_in[10];

    float* out = (float*)d_out;
    float* ws  = (float*)d_ws;

    float* wr    = ws;
    float* wi    = wr + HN;
    float* cr    = wi + HN;
    float* ci    = cr + HN;
    float* w64r  = ci + HN;
    float* w64i  = w64r + HN;
    float* zbuf  = w64i + HN;                      // (H,L) normalized z
    float* psum  = zbuf + (size_t)H * L;           // (NSTRIPE,L)
    float* psq   = psum + (size_t)NSTRIPE * L;
    ushort* yb  = (ushort*)(psq + (size_t)NSTRIPE * L);   // (H,L) bf16
    ushort* wbf = yb + (size_t)H * L;                     // (2H,HP) bf16

    pre_kernel<<<(2 * H * HP + 255) / 256, 256, 0, stream>>>(
        log_dt, A_real_log, A_imag, C_re, C_im, glu_w,
        wr, wi, cr, ci, w64r, w64i, wbf);

    const dim3 gg(L / GBN, (H + 31) / 32);
    const dim3 lg(L / 64, NSTRIPE);

    for (int layer = 0; layer < NLAYERS; ++layer) {
        const int donorm = (layer > 0);
        const float* zsrc = (layer == 0) ? Z : out;

        // conv: normalizes input inline (using prev-layer stats), writes the
        // normalized z to zbuf (residual source) and gelu(conv) to yb.
        conv_fused<<<H, 1024, 0, stream>>>(
            zsrc, psum, psq, ln_g, ln_b, donorm,
            wr, wi, cr, ci, w64r, w64i, D_skip, zbuf, yb);

        // glu: reads zbuf residual, writes zpre -> out and THIS layer's stats
        // (conv above consumed the previous stats before this overwrites).
        glu_mfma<<<gg, 256, 0, stream>>>(wbf, yb, glu_b, zbuf, out, psum, psq);
    }
    // final LN in place on out (layer-3 stats).
    ln_apply<<<lg, 256, 0, stream>>>(psum, psq, ln_g, ln_b, out);
}

// Round 15
// 219.166 us; speedup vs baseline: 1.0937x; 1.0937x over previous
//
#include <hip/hip_runtime.h>
#include <hip/hip_bf16.h>
#include <math.h>

#define H 511
#define L 2048
#define NST 32
#define NLAYERS 4
#define LN_EPS 1e-5f
#define NCH 32             // chunks per channel (conv)
#define TC (L / NCH)       // 64 steps per chunk
#define HN (H * NST)       // 16352
#define HP 512             // K padded
#define GBK 64
#define GBN 64
#define NSTRIPE 16         // LN h-stripes of 32

typedef __attribute__((ext_vector_type(8))) short short8;
typedef __attribute__((ext_vector_type(4))) float f32x4;

__device__ __forceinline__ ushort f2bf(float v) {
    __hip_bfloat16 b = __float2bfloat16(v);
    return *reinterpret_cast<ushort*>(&b);
}

// ---------------------------------------------------------------------------
// DPP helpers: sum across each 32-lane half; result lands in lanes 31 and 63.
// ---------------------------------------------------------------------------
template <int CTRL, int ROW_MASK>
__device__ __forceinline__ float dpp_add(float x) {
    int r = __builtin_amdgcn_update_dpp(0, __float_as_int(x), CTRL, ROW_MASK, 0xf, true);
    return x + __int_as_float(r);
}
__device__ __forceinline__ float reduce32_to_lane31(float p) {
    p = dpp_add<0x111, 0xf>(p);  // row_shr:1
    p = dpp_add<0x112, 0xf>(p);  // row_shr:2
    p = dpp_add<0x114, 0xf>(p);  // row_shr:4
    p = dpp_add<0x118, 0xf>(p);  // row_shr:8
    p = dpp_add<0x142, 0xa>(p);  // row_bcast:15 into rows 1,3
    return p;                    // lane31 = sum(0..31), lane63 = sum(32..63)
}

__device__ __forceinline__ float gelu_tanh(float v) {
    const float c0 = 0.7978845608028654f;  // sqrt(2/pi)
    float t = tanhf(c0 * (v + 0.044715f * v * v * v));
    return 0.5f * v * (1.0f + t);
}

// ---------------------------------------------------------------------------
// Fused conv (round-8/10 proven structure) + merged precompute on layer 0:
// when dopre: block h computes its own channel's coefs (lanes 0..31) into
// LDS + global, and converts its 1024-element slice of W -> wbf (grid covers
// 2H*HP exactly). One block = ONE channel, 1024 thr = 32 chunks of 64 steps.
// ---------------------------------------------------------------------------
__global__ __launch_bounds__(1024) void conv_fused(
    const float* __restrict__ z,       // (H,L) fp32
    const int dopre,
    const float* __restrict__ log_dt,
    const float* __restrict__ A_real_log,
    const float* __restrict__ A_imag,
    const float* __restrict__ C_re,
    const float* __restrict__ C_im,
    const float* __restrict__ W,       // (2H,H) glu weight (dopre only)
    float* __restrict__ wr_,
    float* __restrict__ wi_,
    float* __restrict__ cr_,
    float* __restrict__ ci_,
    const float* __restrict__ D_skip,
    ushort* __restrict__ wbf,          // (2H,HP) bf16 out (dopre only)
    ushort* __restrict__ yb)           // (H,L) bf16
{
    __shared__ float zs[L];            // 8 KB
    __shared__ float ber[NCH][NST];    // 4 KB
    __shared__ float bei[NCH][NST];    // 4 KB
    __shared__ float ysf[L];           // 8 KB
    __shared__ float swr[NST], swi[NST], scr[NST], sci[NST];

    const int tid  = threadIdx.x;
    const int wv   = tid >> 6;          // wave 0..15
    const int half = (tid >> 5) & 1;
    const int ln   = tid & 31;          // state index n
    const int c    = wv * 2 + half;     // chunk 0..31
    const int h    = blockIdx.x;

    if (dopre) {
        // W -> bf16 pad: grid covers 2H*HP = 511*1024 exactly
        int idx = h * 1024 + tid;
        {
            int r = idx / HP, k = idx % HP;
            float v = (k < H) ? W[(size_t)r * H + k] : 0.0f;
            wbf[idx] = f2bf(v);
        }
        // own-channel coefs (lanes 0..31 of wave 0)
        if (tid < NST) {
            int ii = h * NST + tid;
            float Ar = -expf(A_real_log[ii]);
            float Ai = A_imag[ii];
            float dt = expf(log_dt[h]);
            float dr = Ar * dt, di = Ai * dt;
            float er = expf(dr);
            float wrv = er * cosf(di);
            float wiv = er * sinf(di);
            float den = Ar * Ar + Ai * Ai;
            float a = wrv - 1.0f, b = wiv;
            float inv = 1.0f / den;
            float qr = (a * Ar + b * Ai) * inv;
            float qi = (b * Ar - a * Ai) * inv;
            float crv = 2.0f * (C_re[ii] * qr - C_im[ii] * qi);
            float civ = 2.0f * (C_re[ii] * qi + C_im[ii] * qr);
            wr_[ii] = wrv; wi_[ii] = wiv; cr_[ii] = crv; ci_[ii] = civ;
            swr[tid] = wrv; swi[tid] = wiv; scr[tid] = crv; sci[tid] = civ;
        }
    }

    // stage z row: 2048 floats, one float2 per thread, coalesced
    *(float2*)&zs[tid * 2] = *(const float2*)&z[(size_t)h * L + tid * 2];
    __syncthreads();

    float wr, wi, cr, ci;
    if (dopre) {
        wr = swr[ln]; wi = swi[ln]; cr = scr[ln]; ci = sci[ln];
    } else {
        const int cidx = h * NST + ln;
        wr = wr_[cidx]; wi = wi_[cidx]; cr = cr_[cidx]; ci = ci_[cidx];
    }
    const float Dh = D_skip[h];

    // phase 1: local scan of chunk c (carry 0)
    float sr = 0.f, si = 0.f;
    {
        const float* zp = &zs[c * TC];
        #pragma unroll 4
        for (int l = 0; l < TC; ++l) {
            float zl = zp[l];
            float nsr = fmaf(wr, sr, fmaf(-wi, si, zl));
            float nsi = fmaf(wr, si, wi * sr);
            sr = nsr; si = nsi;
        }
    }
    ber[c][ln] = sr;
    bei[c][ln] = si;
    __syncthreads();

    // phase 2: threads 0..31 (lane n) combine the 32 chunk states
    if (tid < 32) {
        float wtr = wr, wti = wi;
        #pragma unroll
        for (int k = 0; k < 6; ++k) {      // w^64
            float nr = wtr * wtr - wti * wti;
            float ni = 2.0f * wtr * wti;
            wtr = nr; wti = ni;
        }
        float er = 0.f, ei = 0.f;
        #pragma unroll
        for (int cc = 0; cc < NCH; ++cc) {
            float s_r = ber[cc][tid], s_i = bei[cc][tid];
            ber[cc][tid] = er; bei[cc][tid] = ei;   // carry-in for chunk cc
            float ner = fmaf(wtr, er, fmaf(-wti, ei, s_r));
            float nei = fmaf(wtr, ei, fmaf(wti, er, s_i));
            er = ner; ei = nei;
        }
    }
    __syncthreads();

    // phase 3: rescan with carry + C-dot + reduce + D-skip (preactivation)
    sr = ber[c][ln];
    si = bei[c][ln];
    {
        const float* zp = &zs[c * TC];
        float* yp = &ysf[c * TC];
        for (int l = 0; l < TC; ++l) {
            float zl = zp[l];
            float nsr = fmaf(wr, sr, fmaf(-wi, si, zl));
            float nsi = fmaf(wr, si, wi * sr);
            sr = nsr; si = nsi;
            float p = fmaf(cr, sr, -ci * si);
            p = reduce32_to_lane31(p);
            if (ln == 31) yp[l] = fmaf(Dh, zl, p);
        }
    }
    __syncthreads();

    // epilogue: all lanes, gelu + bf16, coalesced ushort2 stores
    {
        ushort2 v;
        v.x = f2bf(gelu_tanh(ysf[tid * 2]));
        v.y = f2bf(gelu_tanh(ysf[tid * 2 + 1]));
        *(ushort2*)&yb[(size_t)h * L + tid * 2] = v;
    }
}

// ---------------------------------------------------------------------------
// MFMA GLU GEMM + fused LN-stats (round-10 proven, unchanged).
// ---------------------------------------------------------------------------
__global__ __launch_bounds__(256) void glu_mfma(
    const ushort* __restrict__ wbf,   // (2H, HP) bf16
    const ushort* __restrict__ yb,    // (H, L) bf16
    const float* __restrict__ bias,   // (2H)
    const float* __restrict__ zres,   // (H,L)
    float* __restrict__ out,          // (H,L)
    float* __restrict__ psum,         // (NSTRIPE,L)
    float* __restrict__ psq)          // (NSTRIPE,L)
{
    __shared__ ushort As1[32 * GBK];       // 4 KB
    __shared__ ushort As2[32 * GBK];       // 4 KB
    __shared__ ushort Bs[GBN * GBK];       // 8 KB
    __shared__ ushort tempT[4][32 * 40];   // 10 KB
    __shared__ float  sls[2][64];
    __shared__ float  slq[2][64];

    const int tid = threadIdx.x;
    const int h0 = blockIdx.y * 32;
    const int l0 = blockIdx.x * GBN;
    const int wid = tid >> 6;
    const int lane = tid & 63;
    const int wrow = (wid >> 1) * 16;
    const int wcol = (wid & 1) * 32;

    f32x4 acc1[2] = {{0.f,0.f,0.f,0.f},{0.f,0.f,0.f,0.f}};
    f32x4 acc2[2] = {{0.f,0.f,0.f,0.f},{0.f,0.f,0.f,0.f}};

    const int ar = tid >> 3;
    const int ak = tid & 7;
    const int hq1 = (h0 + ar < H) ? (h0 + ar) : (H - 1);
    const int hq2 = hq1 + H;
    const int aswz = ak ^ (ar & 7);

    const int tm   = tid >> 6;
    const int t64  = tid & 63;
    const int ksub = (tm & 1) * 32;
    const int lsub = (tm >> 1) * 32;
    const int bkl  = t64 >> 1;
    const int bhalf= t64 & 1;
    const int blr  = t64 >> 1;
    const int bkh  = t64 & 1;

    for (int k0 = 0; k0 < HP; k0 += GBK) {
        {
            short8 va1 = *(const short8*)&wbf[(size_t)hq1 * HP + k0 + ak * 8];
            short8 va2 = *(const short8*)&wbf[(size_t)hq2 * HP + k0 + ak * 8];
            *(short8*)&As1[ar * GBK + aswz * 8] = va1;
            *(short8*)&As2[ar * GBK + aswz * 8] = va2;
        }
        {
            const int kg = k0 + ksub + bkl;
            short8 v0 = {0,0,0,0,0,0,0,0}, v1 = {0,0,0,0,0,0,0,0};
            if (kg < H) {
                const ushort* row = &yb[(size_t)kg * L + l0 + lsub + bhalf * 16];
                v0 = *(const short8*)&row[0];
                v1 = *(const short8*)&row[8];
            }
            ushort* tp = &tempT[tm][0];
            #pragma unroll
            for (int j = 0; j < 8; ++j)
                tp[(bhalf * 16 + j) * 40 + bkl] = (ushort)v0[j];
            #pragma unroll
            for (int j = 0; j < 8; ++j)
                tp[(bhalf * 16 + 8 + j) * 40 + bkl] = (ushort)v1[j];
        }
        __syncthreads();
        {
            const ushort* tp = &tempT[tm][0];
            short8 b0 = *(const short8*)&tp[blr * 40 + bkh * 16];
            short8 b1 = *(const short8*)&tp[blr * 40 + bkh * 16 + 8];
            const int L_ = lsub + blr;
            const int kg0 = (ksub >> 3) + bkh * 2;
            *(short8*)&Bs[L_ * GBK + ((kg0    ) ^ (L_ & 7)) * 8] = b0;
            *(short8*)&Bs[L_ * GBK + ((kg0 + 1) ^ (L_ & 7)) * 8] = b1;
        }
        __syncthreads();

        #pragma unroll
        for (int kk = 0; kk < 2; ++kk) {
            const int arow = wrow + (lane & 15);
            const int kg = kk * 4 + (lane >> 4);
            short8 a1 = *(const short8*)&As1[arow * GBK + (kg ^ (arow & 7)) * 8];
            short8 a2 = *(const short8*)&As2[arow * GBK + (kg ^ (arow & 7)) * 8];
            #pragma unroll
            for (int nf = 0; nf < 2; ++nf) {
                const int brow = wcol + nf * 16 + (lane & 15);
                short8 b = *(const short8*)&Bs[brow * GBK + (kg ^ (brow & 7)) * 8];
                acc1[nf] = __builtin_amdgcn_mfma_f32_16x16x32_bf16(a1, b, acc1[nf], 0, 0, 0);
                acc2[nf] = __builtin_amdgcn_mfma_f32_16x16x32_bf16(a2, b, acc2[nf], 0, 0, 0);
            }
        }
        __syncthreads();
    }

    // ---- epilogue: GLU + residual -> out, plus LN partial stats ----
    float ps[2] = {0.f, 0.f}, pq[2] = {0.f, 0.f};
    #pragma unroll
    for (int nf = 0; nf < 2; ++nf) {
        const int col = l0 + wcol + nf * 16 + (lane & 15);
        #pragma unroll
        for (int r = 0; r < 4; ++r) {
            const int h = h0 + wrow + (lane >> 4) * 4 + r;
            if (h < H) {
                float v1 = acc1[nf][r] + bias[h];
                float v2 = acc2[nf][r] + bias[h + H];
                float o = v1 * (1.0f / (1.0f + expf(-v2))) + zres[(size_t)h * L + col];
                out[(size_t)h * L + col] = o;
                ps[nf] += o;
                pq[nf] = fmaf(o, o, pq[nf]);
            }
        }
    }
    #pragma unroll
    for (int nf = 0; nf < 2; ++nf) {
        ps[nf] += __shfl_xor(ps[nf], 16, 64);
        ps[nf] += __shfl_xor(ps[nf], 32, 64);
        pq[nf] += __shfl_xor(pq[nf], 16, 64);
        pq[nf] += __shfl_xor(pq[nf], 32, 64);
        if ((lane >> 4) == 0) {
            int cl = wcol + nf * 16 + lane;
            sls[wid >> 1][cl] = ps[nf];
            slq[wid >> 1][cl] = pq[nf];
        }
    }
    __syncthreads();
    if (tid < 64) {
        psum[(size_t)blockIdx.y * L + l0 + tid] = sls[0][tid] + sls[1][tid];
        psq [(size_t)blockIdx.y * L + l0 + tid] = slq[0][tid] + slq[1][tid];
    }
}

// ---------------------------------------------------------------------------
// LN apply (round-10 proven): fold partials -> mu/rstd; apply stripe.
// ---------------------------------------------------------------------------
__global__ __launch_bounds__(256) void ln_apply(
    const float* __restrict__ zpre,
    const float* __restrict__ psum, const float* __restrict__ psq,
    const float* __restrict__ g, const float* __restrict__ b,
    float* __restrict__ out)
{
    const int tx = threadIdx.x & 63;
    const int ty = threadIdx.x >> 6;
    const int l = blockIdx.x * 64 + tx;
    const int s = blockIdx.y;

    float S = 0.f, Q = 0.f;
    #pragma unroll
    for (int k = 0; k < NSTRIPE; ++k) {
        S += psum[(size_t)k * L + l];
        Q += psq[(size_t)k * L + l];
    }
    const float invH = 1.0f / (float)H;
    float mu = S * invH;
    float var = Q * invH - mu * mu;
    float rstd = rsqrtf(var + LN_EPS);

    const int hbase = s * 32;
    #pragma unroll
    for (int j = 0; j < 8; ++j) {
        int h = hbase + ty + j * 4;
        if (h < H) {
            float v = zpre[(size_t)h * L + l];
            out[(size_t)h * L + l] = (v - mu) * rstd * g[h] + b[h];
        }
    }
}

// ---------------------------------------------------------------------------
extern "C" void kernel_launch(void* const* d_in, const int* in_sizes, int n_in,
                              void* d_out, int out_size, void* d_ws, size_t ws_size,
                              hipStream_t stream) {
    const float* Z          = (const float*)d_in[0];
    const float* log_dt     = (const float*)d_in[1];
    const float* A_real_log = (const float*)d_in[2];
    const float* A_imag     = (const float*)d_in[3];
    const float* C_re       = (const float*)d_in[4];
    const float* C_im       = (const float*)d_in[5];
    const float* D_skip     = (const float*)d_in[6];
    const float* glu_w      = (const float*)d_in[7];
    const float* glu_b      = (const float*)d_in[8];
    const float* ln_g       = (const float*)d_in[9];
    const float* ln_b       = (const float*)d_in[10];

    float* out = (float*)d_out;
    float* ws  = (float*)d_ws;

    float* wr   = ws;
    float* wi   = wr + HN;
    float* cr   = wi + HN;
    float* ci   = cr + HN;
    float* zbuf = ci + HN;                        // (H,L) fp32
    float* psum = zbuf + (size_t)H * L;           // (NSTRIPE,L)
    float* psq  = psum + (size_t)NSTRIPE * L;
    ushort* yb  = (ushort*)(psq + (size_t)NSTRIPE * L);   // (H,L) bf16
    ushort* wbf = yb + (size_t)H * L;                     // (2H,HP) bf16

    const dim3 gg(L / GBN, (H + 31) / 32);
    const dim3 lg(L / 64, NSTRIPE);

    for (int layer = 0; layer < NLAYERS; ++layer) {
        const float* zcur = (layer == 0) ? Z : zbuf;

        conv_fused<<<H, 1024, 0, stream>>>(
            zcur, (layer == 0) ? 1 : 0,
            log_dt, A_real_log, A_imag, C_re, C_im, glu_w,
            wr, wi, cr, ci, D_skip, wbf, yb);
        glu_mfma<<<gg, 256, 0, stream>>>(wbf, yb, glu_b, zcur, out, psum, psq);

        float* lnout = (layer < NLAYERS - 1) ? zbuf : out;
        ln_apply<<<lg, 256, 0, stream>>>(out, psum, psq, ln_g, ln_b, lnout);
    }
}